// Round 3
// baseline (12880.904 us; speedup 1.0000x reference)
//
#include <hip/hip_runtime.h>
#include <math.h>

#define BB 64
#define TT 128
#define II 4096
#define HH 1024
#define NG 4096   // 4*H
#define KS 2048   // recurrent K: [h | c]
#define NBLK 256
#define WPAD 2056 // 2048 + 8 shorts LDS pad

typedef __attribute__((ext_vector_type(8))) short short8;
typedef __attribute__((ext_vector_type(4))) float f32x4;
typedef __attribute__((ext_vector_type(4))) unsigned short ushort4v;
typedef __attribute__((ext_vector_type(8))) unsigned short ushort8v;

__device__ __forceinline__ unsigned short f2bf(float f){
  union { float f; unsigned u; } v; v.f = f;
  unsigned r = v.u + 0x7fffu + ((v.u >> 16) & 1u);   // RNE
  return (unsigned short)(r >> 16);
}
__device__ __forceinline__ float bf2f(unsigned short u){
  union { float f; unsigned u; } v; v.u = ((unsigned)u) << 16;
  return v.f;
}
__device__ __forceinline__ float sigm(float x){ return 1.f/(1.f + expf(-x)); }

// ---------------- conversion / layout kernels ----------------

__global__ void conv_x(const float* __restrict__ in, unsigned short* __restrict__ outb){
  const size_t i = ((size_t)blockIdx.x*256 + threadIdx.x)*4;
  f32x4 v = *(const f32x4*)(&in[i]);
  ushort4v o; o[0]=f2bf(v[0]); o[1]=f2bf(v[1]); o[2]=f2bf(v[2]); o[3]=f2bf(v[3]);
  *(ushort4v*)(&outb[i]) = o;
}

// W (4,H,ncols) -> Wil[n'=4h+g][0:ncols], bf16 (gate-interleaved rows)
__global__ void build_Wil(const float* __restrict__ src, unsigned short* __restrict__ dst, int ncols){
  const int row = blockIdx.y;
  const int c4 = (blockIdx.x*256 + threadIdx.x)*4;
  const int g = row & 3, h = row >> 2;
  f32x4 v = *(const f32x4*)(&src[((size_t)(g*HH + h))*ncols + c4]);
  ushort4v o; o[0]=f2bf(v[0]); o[1]=f2bf(v[1]); o[2]=f2bf(v[2]); o[3]=f2bf(v[3]);
  *(ushort4v*)(&dst[(size_t)row*ncols + c4]) = o;
}

// Wcat[n'=4k+g][0:1024]=Uh[g][k][:], [1024:2048]=Vc[j][k][:] (0 for g==2)
__global__ void build_Wcat(const float* __restrict__ Uh, const float* __restrict__ Vc,
                           unsigned short* __restrict__ Wc){
  const int row = blockIdx.y;
  const int c4 = (blockIdx.x*256 + threadIdx.x)*4;
  const int g = row & 3, k = row >> 2;
  f32x4 v;
  if (c4 < HH)      v = *(const f32x4*)(&Uh[((size_t)(g*HH + k))*HH + c4]);
  else if (g == 2)  v = f32x4{0.f,0.f,0.f,0.f};
  else { const int jj = (g==3)?2:g;
         v = *(const f32x4*)(&Vc[((size_t)(jj*HH + k))*HH + (c4 - HH)]); }
  ushort4v o; o[0]=f2bf(v[0]); o[1]=f2bf(v[1]); o[2]=f2bf(v[2]); o[3]=f2bf(v[3]);
  *(ushort4v*)(&Wc[(size_t)row*KS + c4]) = o;
}

__global__ void init_state(const float* __restrict__ h0, const float* __restrict__ c0,
  float* ha_f, float* ca_f, float* hb_f, float* cb_f,
  unsigned short* A0w, unsigned short* A1w){
  const int idx = blockIdx.x*256 + threadIdx.x;   // < 65536
  const int b = idx >> 10, k = idx & 1023;
  const float ha = h0[idx], ca = c0[idx];
  const float hb = h0[BB*HH + idx], cb = c0[BB*HH + idx];
  ha_f[idx]=ha; ca_f[idx]=ca; hb_f[idx]=hb; cb_f[idx]=cb;
  A0w[b*KS + k]        = f2bf(ha);
  A0w[b*KS + HH + k]   = f2bf(ca);
  A1w[b*KS + k]        = f2bf(hb);
  A1w[b*KS + HH + k]   = f2bf(cb);
}

__global__ void finalize(const float* ha_f, const float* hb_f, const float* ca_f, const float* cb_f,
                         float* __restrict__ outp){
  const int idx = blockIdx.x*256 + threadIdx.x;   // < 65536
  outp[idx]            = ha_f[idx];
  outp[BB*HH + idx]    = hb_f[idx];
  outp[2*BB*HH + idx]  = ca_f[idx];
  outp[3*BB*HH + idx]  = cb_f[idx];
}

// ---------------- big GEMM: C = A . Wt^T + bias (gate-interleaved), bf16 out ----------------
__global__ __launch_bounds__(256) void gemm_big(
  const unsigned short* __restrict__ A, const unsigned short* __restrict__ Wt,
  const float* __restrict__ bias, unsigned short* __restrict__ C, int lda)
{
  __shared__ __align__(16) unsigned short Asm[128*72];
  __shared__ __align__(16) unsigned short Wsm[128*72];
  const int tid = threadIdx.x, lane = tid & 63, w = tid >> 6;
  const int wr = w >> 1, wc = w & 1;
  const int m0 = blockIdx.y * 128, n0 = blockIdx.x * 128;
  const int rA = tid >> 3, c8 = (tid & 7) * 8;

  f32x4 acc[4][4];
  #pragma unroll
  for (int i=0;i<4;i++)
    #pragma unroll
    for (int j=0;j<4;j++) acc[i][j] = f32x4{0.f,0.f,0.f,0.f};

  ushort8v pa[4], pw[4];
  #pragma unroll
  for (int s=0;s<4;s++){
    pa[s] = *(const ushort8v*)(&A [(size_t)(m0 + rA + 32*s)*lda + c8]);
    pw[s] = *(const ushort8v*)(&Wt[(size_t)(n0 + rA + 32*s)*lda + c8]);
  }
  for (int kt = 0; kt < lda; kt += 64) {
    __syncthreads();
    #pragma unroll
    for (int s=0;s<4;s++){
      *(ushort8v*)(&Asm[(rA+32*s)*72 + c8]) = pa[s];
      *(ushort8v*)(&Wsm[(rA+32*s)*72 + c8]) = pw[s];
    }
    __syncthreads();
    if (kt + 64 < lda){
      #pragma unroll
      for (int s=0;s<4;s++){
        pa[s] = *(const ushort8v*)(&A [(size_t)(m0 + rA + 32*s)*lda + kt + 64 + c8]);
        pw[s] = *(const ushort8v*)(&Wt[(size_t)(n0 + rA + 32*s)*lda + kt + 64 + c8]);
      }
    }
    #pragma unroll
    for (int ks=0; ks<2; ks++){
      const int kk = ks*32 + (lane>>4)*8;
      short8 af[4], bfv[4];
      #pragma unroll
      for (int rt=0; rt<4; rt++)
        af[rt] = *(const short8*)(&Asm[(wr*64 + rt*16 + (lane&15))*72 + kk]);
      #pragma unroll
      for (int ct=0; ct<4; ct++)
        bfv[ct] = *(const short8*)(&Wsm[(wc*64 + ct*16 + (lane&15))*72 + kk]);
      #pragma unroll
      for (int rt=0; rt<4; rt++)
        #pragma unroll
        for (int ct=0; ct<4; ct++)
          acc[rt][ct] = __builtin_amdgcn_mfma_f32_16x16x32_bf16(af[rt], bfv[ct], acc[rt][ct], 0,0,0);
    }
  }
  #pragma unroll
  for (int rt=0; rt<4; rt++){
    #pragma unroll
    for (int ct=0; ct<4; ct++){
      const int n = n0 + wc*64 + ct*16 + (lane&15);
      const float bv = bias[(n&3)*HH + (n>>2)];
      #pragma unroll
      for (int r=0;r<4;r++){
        const int m = m0 + wr*64 + rt*16 + (lane>>4)*4 + r;
        C[(size_t)m*NG + n] = f2bf(acc[rt][ct][r] + bv);
      }
    }
  }
}

// ---------------- persistent recurrent loop (both layers use K=2048) ----------------
// 256 blocks x 16 gate-cols. W slice staged in LDS once; A-state direct from L2.
// bar[0]=arrival counter, bar[16]=generation (separate cache lines).
__global__ __launch_bounds__(256) void lstm_loop(
  const unsigned short* __restrict__ W,     // [4096][2048] gate-interleaved
  const unsigned short* __restrict__ XZ,    // [8192][4096] bf16, bias included
  unsigned short* __restrict__ Sb0,         // ping state [64][2048] = [h|c]
  unsigned short* __restrict__ Sb1,         // pong
  float* __restrict__ c_f, float* __restrict__ h_f,
  unsigned short* __restrict__ hseq,        // loop A: bf16 [ (b*TT+t)*HH + k ], else null
  float* __restrict__ outp,                 // loop B: fp32 output, else null
  unsigned* __restrict__ bar)
{
  __shared__ __align__(16) unsigned short Wlds[16*WPAD];
  __shared__ float preSm[64*17];
  const int tid = threadIdx.x, lane = tid & 63, w = tid >> 6;
  const int n0 = blockIdx.x * 16;
  const int klo = (lane >> 4) * 8;

  // stage this block's 16 W rows (64 KB) into LDS once
  for (int i = tid*8; i < 16*KS; i += 256*8){
    const int r = i >> 11, c = i & (KS-1);
    *(ushort8v*)(&Wlds[r*WPAD + c]) = *(const ushort8v*)(&W[(size_t)(n0 + r)*KS + c]);
  }
  __syncthreads();

  const size_t aoff = (size_t)(w*16 + (lane&15))*KS + klo;
  const unsigned short* Ap0 = Sb0 + aoff;
  const unsigned short* Ap1 = Sb1 + aoff;
  const int wrow = (lane & 15)*WPAD + klo;
  const int b = tid >> 2, v = tid & 3;
  const int kk = blockIdx.x*4 + v;
  const int si = b*HH + kk;

  for (int t = 0; t < TT; ++t){
    const unsigned short* Ar = (t & 1) ? Ap1 : Ap0;
    unsigned short* Aw = (t & 1) ? Sb0 : Sb1;

    f32x4 acc[4];
    #pragma unroll
    for (int c=0;c<4;c++) acc[c] = f32x4{0.f,0.f,0.f,0.f};
    #pragma unroll 4
    for (int kt = 0; kt < KS; kt += 128){
      #pragma unroll
      for (int c = 0; c < 4; ++c){
        short8 av = *(const short8*)(Ar + kt + c*32);
        short8 bv = *(const short8*)(&Wlds[wrow + kt + c*32]);
        acc[c] = __builtin_amdgcn_mfma_f32_16x16x32_bf16(av, bv, acc[c], 0,0,0);
      }
    }
    f32x4 r;
    #pragma unroll
    for (int j=0;j<4;j++) r[j] = acc[0][j]+acc[1][j]+acc[2][j]+acc[3][j];
    #pragma unroll
    for (int j=0;j<4;j++)
      preSm[(w*16 + (lane>>4)*4 + j)*17 + (lane&15)] = r[j];
    __syncthreads();

    float p0 = preSm[b*17 + 4*v + 0];
    float p1 = preSm[b*17 + 4*v + 1];
    float p2 = preSm[b*17 + 4*v + 2];
    float p3 = preSm[b*17 + 4*v + 3];
    ushort4v xz = *(const ushort4v*)(&XZ[((size_t)(b*TT + t))*NG + n0 + 4*v]);
    p0 += bf2f(xz[0]); p1 += bf2f(xz[1]); p2 += bf2f(xz[2]); p3 += bf2f(xz[3]);
    const float ig = sigm(p0), fg = sigm(p1), gg = tanhf(p2), og = sigm(p3);
    const float cn = fg*c_f[si] + ig*gg;
    const float hn = og*tanhf(cn);
    c_f[si] = cn; h_f[si] = hn;
    Aw[b*KS + kk]      = f2bf(hn);
    Aw[b*KS + HH + kk] = f2bf(cn);
    if (hseq) hseq[((size_t)(b*TT + t))*HH + kk] = f2bf(hn);
    if (outp) outp[((size_t)(b*TT + t))*HH + kk] = hn;

    if (t + 1 < TT){
      __syncthreads();   // all state writes of this block issued & drained at barrier
      if (tid == 0){
        __threadfence();  // agent-scope release (L2 writeback for cross-XCD)
        unsigned arrived = __hip_atomic_fetch_add(bar, 1u, __ATOMIC_ACQ_REL, __HIP_MEMORY_SCOPE_AGENT) + 1u;
        if (arrived == (unsigned)((t+1) * NBLK)){
          __hip_atomic_store(bar + 16, (unsigned)(t+1), __ATOMIC_RELEASE, __HIP_MEMORY_SCOPE_AGENT);
        } else {
          while (__hip_atomic_load(bar + 16, __ATOMIC_ACQUIRE, __HIP_MEMORY_SCOPE_AGENT) < (unsigned)(t+1)){
            __builtin_amdgcn_s_sleep(4);
          }
        }
        __threadfence();  // acquire side
      }
      __syncthreads();
    }
  }
}

// ---------------- host ----------------

extern "C" void kernel_launch(void* const* d_in, const int* in_sizes, int n_in,
                              void* d_out, int out_size, void* d_ws, size_t ws_size,
                              hipStream_t stream)
{
  (void)in_sizes; (void)n_in; (void)out_size; (void)ws_size;
  const float* x   = (const float*)d_in[0];
  const float* h0  = (const float*)d_in[1];
  const float* c0  = (const float*)d_in[2];
  const float* Wx0 = (const float*)d_in[3];
  const float* Uh0 = (const float*)d_in[4];
  const float* Vc0 = (const float*)d_in[5];
  const float* b0  = (const float*)d_in[6];
  const float* Wx1 = (const float*)d_in[7];
  const float* Uh1 = (const float*)d_in[8];
  const float* Vc1 = (const float*)d_in[9];
  const float* b1  = (const float*)d_in[10];
  float* out = (float*)d_out;

  char* ws = (char*)d_ws;
  size_t off = 0;
  auto alloc = [&](size_t bytes) { char* p = ws + off; off += (bytes + 255) & ~(size_t)255; return p; };
  unsigned short* x_bf  = (unsigned short*)alloc((size_t)BB*TT*II*2);   // reused as XZ1
  unsigned short* Wx0il = (unsigned short*)alloc((size_t)NG*II*2);      // reused as Hseq + Wx1il
  unsigned short* XZ0   = (unsigned short*)alloc((size_t)BB*TT*NG*2);
  unsigned short* W0cat = (unsigned short*)alloc((size_t)NG*KS*2);
  unsigned short* W1cat = (unsigned short*)alloc((size_t)NG*KS*2);
  unsigned short* A0b[2] = { (unsigned short*)alloc((size_t)BB*KS*2), (unsigned short*)alloc((size_t)BB*KS*2) };
  unsigned short* A1b[2] = { (unsigned short*)alloc((size_t)BB*KS*2), (unsigned short*)alloc((size_t)BB*KS*2) };
  float* ha_f = (float*)alloc((size_t)BB*HH*4);
  float* ca_f = (float*)alloc((size_t)BB*HH*4);
  float* hb_f = (float*)alloc((size_t)BB*HH*4);
  float* cb_f = (float*)alloc((size_t)BB*HH*4);
  unsigned* bar = (unsigned*)alloc(512);

  unsigned short* XZ1   = x_bf;                                     // alias (x_bf dead after gemm_xz0)
  unsigned short* Hseq  = Wx0il;                                    // alias (Wx0il dead after gemm_xz0)
  unsigned short* Wx1il = Wx0il + (size_t)BB*TT*HH;                 // alias, after Hseq (16.8MB + 8.4MB < 33.6MB)

  hipMemsetAsync(bar, 0, 512, stream);
  conv_x<<<32768, 256, 0, stream>>>(x, x_bf);
  build_Wil<<<dim3(4,4096), 256, 0, stream>>>(Wx0, Wx0il, II);
  build_Wcat<<<dim3(2,4096), 256, 0, stream>>>(Uh0, Vc0, W0cat);
  build_Wcat<<<dim3(2,4096), 256, 0, stream>>>(Uh1, Vc1, W1cat);
  init_state<<<256, 256, 0, stream>>>(h0, c0, ha_f, ca_f, hb_f, cb_f, A0b[0], A1b[0]);

  gemm_big<<<dim3(32,64), 256, 0, stream>>>(x_bf, Wx0il, b0, XZ0, II);

  build_Wil<<<dim3(1,4096), 256, 0, stream>>>(Wx1, Wx1il, HH);      // after gemm_xz0 (aliases Wx0il tail)

  lstm_loop<<<NBLK, 256, 0, stream>>>(W0cat, XZ0, A0b[0], A0b[1], ca_f, ha_f,
                                      Hseq, (float*)nullptr, bar);

  gemm_big<<<dim3(32,64), 256, 0, stream>>>(Hseq, Wx1il, b1, XZ1, HH);

  lstm_loop<<<NBLK, 256, 0, stream>>>(W1cat, XZ1, A1b[0], A1b[1], cb_f, hb_f,
                                      (unsigned short*)nullptr, out, bar + 64);

  finalize<<<256, 256, 0, stream>>>(ha_f, hb_f, ca_f, cb_f, out + (size_t)BB*TT*HH);
}